// Round 15
// baseline (115.649 us; speedup 1.0000x reference)
//
#include <hip/hip_runtime.h>
#include <hip/hip_fp16.h>
#include <math.h>

// LatentVoxelGrid: N=65536 pts, M=131072 voxels, K=8 cand, D=64.
// zero_cursor -> prep (zbf/fbf/HBt/bfZ + weight B-frags + per-pair SLOT precompute)
// -> pair (TPW=4 preload-all, MFMA, batched softmax; slot is a plain load)
// -> gather (per-voxel sum -> normalized bf16 msg; msg aliases rec)
// -> stage2 (gate+GRU, B-frags from L2-hot global, LDS = 2KB biases only)

typedef short bf16x8 __attribute__((ext_vector_type(8)));
typedef unsigned short u16x8 __attribute__((ext_vector_type(8)));
typedef float f32x4 __attribute__((ext_vector_type(4)));
#define MFMA __builtin_amdgcn_mfma_f32_16x16x32_bf16
#define CAP 32

__device__ __forceinline__ short f2bf(float f) {  // round-to-nearest-even
  unsigned u = __float_as_uint(f);
  unsigned r = (u + 0x7FFFu + ((u >> 16) & 1u)) >> 16;
  return (short)r;
}

__device__ __forceinline__ float bf2f(unsigned short h) {
  return __uint_as_float(((unsigned)h) << 16);
}

__device__ __forceinline__ float sigm(float x) { return 1.0f / (1.0f + __expf(-x)); }

__global__ __launch_bounds__(256) void zero_cursor(int* __restrict__ c, int m) {
  int n4 = m >> 2;
  int stride = gridDim.x * 256;
  int4* p = (int4*)c;
  for (int j = blockIdx.x * 256 + threadIdx.x; j < n4; j += stride)
    p[j] = make_int4(0, 0, 0, 0);
}

// ---- prep: zbf, bfZ/GF/WihF/WhhF packs, slot precompute, HBt + fbf ----
__global__ __launch_bounds__(256) void prep_kernel(
    const float* __restrict__ z, const float* __restrict__ f,
    const float* __restrict__ sim_w1, const float* __restrict__ sim_b1,
    const float* __restrict__ gate_w1, const float* __restrict__ W_ih,
    const float* __restrict__ W_hh, const int* __restrict__ cand,
    unsigned short* __restrict__ zbf, unsigned short* __restrict__ fbf,
    unsigned short* __restrict__ HBt, short* __restrict__ bfZ,
    short* __restrict__ GF, short* __restrict__ WihF, short* __restrict__ WhhF,
    int* __restrict__ slotbuf, int* __restrict__ cursor, int M, long npairs)
{
  long tid = (long)blockIdx.x * 256 + threadIdx.x;
  long nthr = (long)gridDim.x * 256;

  // per-pair slot precompute (cursor pre-zeroed by zero_cursor)
  for (long i = tid; i < npairs; i += nthr)
    slotbuf[i] = atomicAdd(&cursor[cand[i]], 1);

  long nz = (long)M * 64;
  for (long i = tid * 8; i < nz; i += nthr * 8) {
    float4 a = *(const float4*)&z[i];
    float4 b4 = *(const float4*)&z[i + 4];
    u16x8 o;
    o[0] = (unsigned short)f2bf(a.x);  o[1] = (unsigned short)f2bf(a.y);
    o[2] = (unsigned short)f2bf(a.z);  o[3] = (unsigned short)f2bf(a.w);
    o[4] = (unsigned short)f2bf(b4.x); o[5] = (unsigned short)f2bf(b4.y);
    o[6] = (unsigned short)f2bf(b4.z); o[7] = (unsigned short)f2bf(b4.w);
    *(u16x8*)&zbf[i] = o;
  }

  if (blockIdx.x == gridDim.x - 1 && threadIdx.x < 64) {  // sim_w1 z-part frags
    int lane = threadIdx.x;
    int lr = lane & 15, lg = lane >> 4;
#pragma unroll
    for (int ct = 0; ct < 4; ++ct)
#pragma unroll
      for (int kt = 0; kt < 3; ++kt) {
        bf16x8 b;
#pragma unroll
        for (int e = 0; e < 8; ++e) {
          int k = kt * 32 + lg * 8 + e;  // 0..95: [z(64) | delta(3) | pad]
          float v = (k < 67) ? sim_w1[(64 + k) * 64 + ct * 16 + lr] : 0.0f;
          b[e] = f2bf(v);
        }
        *(bf16x8*)&bfZ[(ct * 3 + kt) * 512 + lane * 8] = b;
      }
  }

  if (blockIdx.x >= 1024 && blockIdx.x < 1040) {  // stage2 weight B-frags
    int fb = (blockIdx.x - 1024) * 4 + (threadIdx.x >> 6);  // 0..63
    int lane = threadIdx.x & 63, lr = lane & 15, lg = lane >> 4;
    bf16x8 o;
    if (fb < 16) {            // gate_w1 (128,64): frag = ct*4+kt
      int ct = fb >> 2, kt = fb & 3;
#pragma unroll
      for (int e = 0; e < 8; ++e)
        o[e] = f2bf(gate_w1[(kt * 32 + lg * 8 + e) * 64 + ct * 16 + lr]);
      *(bf16x8*)&GF[fb * 512 + lane * 8] = o;
    } else if (fb < 40) {     // W_ih (192,64): frag = g*8 + ct*2 + k2
      int q = fb - 16, g = q >> 3, ct = (q >> 1) & 3, k2 = q & 1;
      int row = g * 64 + ct * 16 + lr;
#pragma unroll
      for (int e = 0; e < 8; ++e)
        o[e] = f2bf(W_ih[row * 64 + k2 * 32 + lg * 8 + e]);
      *(bf16x8*)&WihF[q * 512 + lane * 8] = o;
    } else {                  // W_hh (192,64)
      int q = fb - 40, g = q >> 3, ct = (q >> 1) & 3, k2 = q & 1;
      int row = g * 64 + ct * 16 + lr;
#pragma unroll
      for (int e = 0; e < 8; ++e)
        o[e] = f2bf(W_hh[row * 64 + k2 * 32 + lg * 8 + e]);
      *(bf16x8*)&WhhF[q * 512 + lane * 8] = o;
    }
  }

  if (blockIdx.x < 1024) {  // hb: wave handles 16 point-rows; also writes fbf
    int wave = blockIdx.x * 4 + (threadIdx.x >> 6);
    int lane = threadIdx.x & 63;
    int lr = lane & 15, lg = lane >> 4;
    int n0 = wave * 16;

    bf16x8 bf[8];  // f-part B frags (sim_w1 is L2-hot)
#pragma unroll
    for (int ct = 0; ct < 4; ++ct)
#pragma unroll
      for (int kt = 0; kt < 2; ++kt) {
        bf16x8 bb;
#pragma unroll
        for (int e = 0; e < 8; ++e)
          bb[e] = f2bf(sim_w1[(kt * 32 + lg * 8 + e) * 64 + ct * 16 + lr]);
        bf[ct * 2 + kt] = bb;
      }

    bf16x8 a[2];
#pragma unroll
    for (int kt = 0; kt < 2; ++kt) {
      const float* src = &f[(long)(n0 + lr) * 64 + kt * 32 + lg * 8];
      float4 v0 = *(const float4*)src;
      float4 v1 = *(const float4*)(src + 4);
      bf16x8 t;
      t[0] = f2bf(v0.x); t[1] = f2bf(v0.y); t[2] = f2bf(v0.z); t[3] = f2bf(v0.w);
      t[4] = f2bf(v1.x); t[5] = f2bf(v1.y); t[6] = f2bf(v1.z); t[7] = f2bf(v1.w);
      a[kt] = t;
    }
    *(bf16x8*)&fbf[(long)(n0 + lr) * 64 + lg * 8] = a[0];
    *(bf16x8*)&fbf[(long)(n0 + lr) * 64 + 32 + lg * 8] = a[1];

    f32x4 acc[4] = {{0,0,0,0},{0,0,0,0},{0,0,0,0},{0,0,0,0}};
#pragma unroll
    for (int ct = 0; ct < 4; ++ct) {
      acc[ct] = MFMA(a[0], bf[ct * 2 + 0], acc[ct], 0, 0, 0);
      acc[ct] = MFMA(a[1], bf[ct * 2 + 1], acc[ct], 0, 0, 0);
    }
    float b10 = sim_b1[lr], b11 = sim_b1[16 + lr];
    float b12 = sim_b1[32 + lr], b13 = sim_b1[48 + lr];
#pragma unroll
    for (int e = 0; e < 4; ++e) {
      unsigned lo = (unsigned)(unsigned short)f2bf(acc[0][e] + b10)
                  | ((unsigned)(unsigned short)f2bf(acc[1][e] + b11) << 16);
      unsigned hi = (unsigned)(unsigned short)f2bf(acc[2][e] + b12)
                  | ((unsigned)(unsigned short)f2bf(acc[3][e] + b13) << 16);
      *(uint2*)&HBt[(long)(n0 + lg * 4 + e) * 64 + lr * 4] = make_uint2(lo, hi);
    }
  }
}

// ---- pair: preload all tiles -> MFMA all -> batched softmax -> records ----
#define TPW 4
__global__ __launch_bounds__(256) void pair_kernel(
    const float* __restrict__ pts, const unsigned short* __restrict__ zbf,
    const float* __restrict__ centers, const int* __restrict__ cand_idx,
    const float* __restrict__ sim_w2, const short* __restrict__ bfZ,
    const unsigned short* __restrict__ HBt,
    const int* __restrict__ slotbuf, unsigned* __restrict__ rec)
{
  int wave = (blockIdx.x * 256 + threadIdx.x) >> 6;
  int lane = threadIdx.x & 63;
  int lr = lane & 15, lg = lane >> 4;

  // lane owns the record of pair wave*64+lane (tile lg, row lr)
  int call = cand_idx[wave * 64 + lane];
  int slot = slotbuf[wave * 64 + lane];  // precomputed: plain coalesced load

  bf16x8 b[12];
#pragma unroll
  for (int i = 0; i < 12; ++i) b[i] = *(const bf16x8*)&bfZ[i * 512 + lane * 8];
  float w2c[4];
#pragma unroll
  for (int ct = 0; ct < 4; ++ct) w2c[ct] = sim_w2[ct * 16 + lr];

  // ---- preload phase: ALL tiles' operands issued back-to-back ----
  int c[TPW];
  bf16x8 a0[TPW], a1[TPW], ad[TPW];
  uint2 h2[TPW];
#pragma unroll
  for (int t = 0; t < TPW; ++t) {
    c[t] = __shfl(call, t * 16 + lr, 64);
    a0[t] = *(const bf16x8*)&zbf[(long)c[t] * 64 + lg * 8];
    a1[t] = *(const bf16x8*)&zbf[(long)c[t] * 64 + 32 + lg * 8];
    h2[t] = *(const uint2*)&HBt[((long)(wave * TPW + t) * 2 + (lg >> 1)) * 64 + lr * 4];
    bf16x8 tt = {0, 0, 0, 0, 0, 0, 0, 0};
    if (lg == 0) {
      int n = (wave * TPW + t) * 2 + (lr >> 3);
      tt[0] = f2bf(pts[n * 3 + 0] - centers[c[t] * 3 + 0]);
      tt[1] = f2bf(pts[n * 3 + 1] - centers[c[t] * 3 + 1]);
      tt[2] = f2bf(pts[n * 3 + 2] - centers[c[t] * 3 + 2]);
    }
    ad[t] = tt;
  }

  // ---- MFMA + w2-dot phase ----
  f32x4 part[TPW];
#pragma unroll
  for (int t = 0; t < TPW; ++t) {
    f32x4 acc[4] = {{0,0,0,0},{0,0,0,0},{0,0,0,0},{0,0,0,0}};
#pragma unroll
    for (int ct = 0; ct < 4; ++ct) {
      acc[ct] = MFMA(a0[t], b[ct * 3 + 0], acc[ct], 0, 0, 0);
      acc[ct] = MFMA(a1[t], b[ct * 3 + 1], acc[ct], 0, 0, 0);
      acc[ct] = MFMA(ad[t], b[ct * 3 + 2], acc[ct], 0, 0, 0);
    }
    float hb[4];
    hb[0] = bf2f((unsigned short)(h2[t].x));
    hb[1] = bf2f((unsigned short)(h2[t].x >> 16));
    hb[2] = bf2f((unsigned short)(h2[t].y));
    hb[3] = bf2f((unsigned short)(h2[t].y >> 16));
    f32x4 p = {0.f, 0.f, 0.f, 0.f};
#pragma unroll
    for (int ct = 0; ct < 4; ++ct)
#pragma unroll
      for (int e = 0; e < 4; ++e)
        p[e] = fmaf(fmaxf(acc[ct][e] + hb[ct], 0.0f), w2c[ct], p[e]);
    part[t] = p;
  }

  // ---- batched softmax phase (4 independent chains) ----
  float wrow[TPW];
#pragma unroll
  for (int t = 0; t < TPW; ++t) {
    f32x4 p = part[t];
#pragma unroll
    for (int m = 1; m <= 8; m <<= 1)
#pragma unroll
      for (int e = 0; e < 4; ++e) p[e] += __shfl_xor(p[e], m, 64);
    float other[4];
#pragma unroll
    for (int e = 0; e < 4; ++e) other[e] = __shfl_xor(p[e], 16, 64);
    float mx = p[0];
#pragma unroll
    for (int e = 1; e < 4; ++e) mx = fmaxf(mx, p[e]);
#pragma unroll
    for (int e = 0; e < 4; ++e) mx = fmaxf(mx, other[e]);
    float ex[4], se = 0.f, so = 0.f;
#pragma unroll
    for (int e = 0; e < 4; ++e) {
      ex[e] = __expf((p[e] - mx) * (1.0f / 0.3f));
      se += ex[e];
      so += __expf((other[e] - mx) * (1.0f / 0.3f));
    }
    float inv = 1.0f / (se + so);
    int srcl = (lane >> 2) << 4;
    float t0 = __shfl(ex[0] * inv, srcl, 64);
    float t1 = __shfl(ex[1] * inv, srcl, 64);
    float t2 = __shfl(ex[2] * inv, srcl, 64);
    float t3 = __shfl(ex[3] * inv, srcl, 64);
    int esel = lane & 3;
    wrow[t] = esel == 0 ? t0 : esel == 1 ? t1 : esel == 2 ? t2 : t3;
  }

  // ---- epilogue: route tile lg's row-lr weight to this lane, write record ----
  float v0 = __shfl(wrow[0], lr, 64);
  float v1 = __shfl(wrow[1], lr, 64);
  float v2 = __shfl(wrow[2], lr, 64);
  float v3 = __shfl(wrow[3], lr, 64);
  float wv = lg == 0 ? v0 : lg == 1 ? v1 : lg == 2 ? v2 : v3;

  if (slot < CAP) {
    int n_pt = wave * 8 + 2 * lg + (lr >> 3);
    unsigned short wh = __half_as_ushort(__float2half(wv));
    rec[(long)call * CAP + slot] = ((unsigned)n_pt << 16) | (unsigned)wh;
  }
}

// ---- gather: msg[v] = (Sum w*f[n]) / (Sum w + eps); msg ALIASES rec rows ----
__global__ __launch_bounds__(256) void gather_kernel(
    const unsigned* __restrict__ rec, const int* __restrict__ cursor,
    const unsigned short* __restrict__ fbf, unsigned short* __restrict__ msg_bf,
    int mvox)
{
  int tid = blockIdx.x * 256 + threadIdx.x;
  int row = tid >> 2, seg = tid & 3;  // 4 threads per voxel, 16 cols each
  if (row >= mvox) return;

  int cnt = cursor[row];
  cnt = cnt < CAP ? cnt : CAP;
  const unsigned* rp = &rec[(long)row * CAP];

  float acc[16];
#pragma unroll
  for (int j = 0; j < 16; ++j) acc[j] = 0.f;
  float ws = 0.f;

  for (int i0 = 0; i0 < cnt; i0 += 4) {
    uint4 r4 = *(const uint4*)&rp[i0];
    unsigned rr0 = r4.x, rr1 = r4.y, rr2 = r4.z, rr3 = r4.w;
#pragma unroll
    for (int j = 0; j < 4; ++j) {
      unsigned r = j == 0 ? rr0 : j == 1 ? rr1 : j == 2 ? rr2 : rr3;
      if (i0 + j < cnt) {
        float w = __half2float(__ushort_as_half((unsigned short)(r & 0xffffu)));
        int n = r >> 16;
        ws += w;
        const u16x8* fp = (const u16x8*)&fbf[(long)n * 64 + seg * 16];
        u16x8 f0 = fp[0], f1 = fp[1];
#pragma unroll
        for (int k = 0; k < 8; ++k) {
          acc[k]     = fmaf(w, bf2f(f0[k]), acc[k]);
          acc[8 + k] = fmaf(w, bf2f(f1[k]), acc[8 + k]);
        }
      }
    }
  }
  float inv = 1.0f / (ws + 1e-6f);
  u16x8 o0, o1;
#pragma unroll
  for (int j = 0; j < 8; ++j) {
    o0[j] = (unsigned short)f2bf(acc[j] * inv);
    o1[j] = (unsigned short)f2bf(acc[8 + j] * inv);
  }
  *(u16x8*)&msg_bf[(long)row * 64 + seg * 16] = o0;
  *(u16x8*)&msg_bf[(long)row * 64 + seg * 16 + 8] = o1;
}

// ---- Stage 2: gate MLP + GRU; weights as L2-hot global B-frags; LDS=biases ----
__global__ __launch_bounds__(512)
__attribute__((amdgpu_waves_per_eu(2)))
void stage2(
    const unsigned short* __restrict__ zbf,
    const short* __restrict__ GF, const short* __restrict__ WihF,
    const short* __restrict__ WhhF,
    const float* __restrict__ gate_b1, const float* __restrict__ gate_w2,
    const float* __restrict__ gate_b2,
    const float* __restrict__ b_ih, const float* __restrict__ b_hh,
    const unsigned short* __restrict__ msg_bf,
    float* __restrict__ out)
{
  __shared__ float gb1s[64], gw2s[64], bihs[192], bhhs[192];
  __shared__ float gb2s;

  int t = threadIdx.x;
  if (t < 64) { gb1s[t] = gate_b1[t]; gw2s[t] = gate_w2[t]; }
  if (t < 192) { bihs[t] = b_ih[t]; bhhs[t] = b_hh[t]; }
  if (t == 0) gb2s = gate_b2[0];
  __syncthreads();

  int wid = t >> 6, lane = t & 63;
  int lr = lane & 15, lg = lane >> 4;

  int rowbase = blockIdx.x * 128 + wid * 16;
  long abase = (long)(rowbase + lr) * 64;
  bf16x8 a0 = *(const bf16x8*)&zbf[abase + lg * 8];
  bf16x8 a1 = *(const bf16x8*)&zbf[abase + 32 + lg * 8];
  bf16x8 a2 = *(const bf16x8*)&msg_bf[abase + lg * 8];
  bf16x8 a3 = *(const bf16x8*)&msg_bf[abase + 32 + lg * 8];

  // ---- pass 1: gate ----
  f32x4 usum = {0.f, 0.f, 0.f, 0.f};
#pragma unroll 1
  for (int ct = 0; ct < 4; ++ct) {
    f32x4 au = {0, 0, 0, 0};
    au = MFMA(a0, *(const bf16x8*)&GF[(ct * 4 + 0) * 512 + lane * 8], au, 0, 0, 0);
    au = MFMA(a1, *(const bf16x8*)&GF[(ct * 4 + 1) * 512 + lane * 8], au, 0, 0, 0);
    au = MFMA(a2, *(const bf16x8*)&GF[(ct * 4 + 2) * 512 + lane * 8], au, 0, 0, 0);
    au = MFMA(a3, *(const bf16x8*)&GF[(ct * 4 + 3) * 512 + lane * 8], au, 0, 0, 0);
    int c = ct * 16 + lr;
#pragma unroll
    for (int e = 0; e < 4; ++e)
      usum[e] += fmaxf(au[e] + gb1s[c], 0.0f) * gw2s[c];
  }
#pragma unroll
  for (int m = 1; m <= 8; m <<= 1)
#pragma unroll
    for (int e = 0; e < 4; ++e) {
      float v = usum[e];
      usum[e] = v + __shfl_xor(v, m, 64);
    }
  float gate[4];
#pragma unroll
  for (int e = 0; e < 4; ++e) gate[e] = sigm(usum[e] + gb2s);

  // ---- pass 2: GRU, write out per ct ----
#pragma unroll 1
  for (int ct = 0; ct < 4; ++ct) {
    f32x4 air = {0,0,0,0}, aiz = {0,0,0,0}, ain = {0,0,0,0};
    f32x4 ahr = {0,0,0,0}, ahz = {0,0,0,0}, ahn = {0,0,0,0};
#pragma unroll
    for (int k2 = 0; k2 < 2; ++k2) {
      bf16x8 amg = k2 ? a3 : a2;
      bf16x8 az_ = k2 ? a1 : a0;
      int base = ct * 2 + k2;
      air = MFMA(amg, *(const bf16x8*)&WihF[(      base) * 512 + lane * 8], air, 0, 0, 0);
      aiz = MFMA(amg, *(const bf16x8*)&WihF[( 8 +  base) * 512 + lane * 8], aiz, 0, 0, 0);
      ain = MFMA(amg, *(const bf16x8*)&WihF[(16 +  base) * 512 + lane * 8], ain, 0, 0, 0);
      ahr = MFMA(az_, *(const bf16x8*)&WhhF[(      base) * 512 + lane * 8], ahr, 0, 0, 0);
      ahz = MFMA(az_, *(const bf16x8*)&WhhF[( 8 +  base) * 512 + lane * 8], ahz, 0, 0, 0);
      ahn = MFMA(az_, *(const bf16x8*)&WhhF[(16 +  base) * 512 + lane * 8], ahn, 0, 0, 0);
    }
    int c = ct * 16 + lr;
#pragma unroll
    for (int e = 0; e < 4; ++e) {
      float zv = bf2f(zbf[(long)(rowbase + lg * 4 + e) * 64 + c]);
      float rr = sigm(air[e] + bihs[c] + ahr[e] + bhhs[c]);
      float zg = sigm(aiz[e] + bihs[64 + c] + ahz[e] + bhhs[64 + c]);
      float nn = tanhf(ain[e] + bihs[128 + c] + rr * (ahn[e] + bhhs[128 + c]));
      float hnew = (1.0f - zg) * nn + zg * zv;
      out[(long)(rowbase + lg * 4 + e) * 64 + c] = zv + gate[e] * (hnew - zv);
    }
  }
}

extern "C" void kernel_launch(void* const* d_in, const int* in_sizes, int n_in,
                              void* d_out, int out_size, void* d_ws, size_t ws_size,
                              hipStream_t stream) {
  const float* f_pts   = (const float*)d_in[0];
  const float* pts     = (const float*)d_in[1];
  const float* z_lat   = (const float*)d_in[2];
  const float* centers = (const float*)d_in[3];
  const int*   cand    = (const int*)d_in[4];
  const float* sim_w1  = (const float*)d_in[5];
  const float* sim_b1  = (const float*)d_in[6];
  const float* sim_w2  = (const float*)d_in[7];
  // d_in[8] = sim_b2: uniform softmax shift, unused
  const float* gate_w1 = (const float*)d_in[9];
  const float* gate_b1 = (const float*)d_in[10];
  const float* gate_w2 = (const float*)d_in[11];
  const float* gate_b2 = (const float*)d_in[12];
  const float* W_ih    = (const float*)d_in[13];
  const float* W_hh    = (const float*)d_in[14];
  const float* b_ih    = (const float*)d_in[15];
  const float* b_hh    = (const float*)d_in[16];

  int N = in_sizes[0] / 64;
  int M = in_sizes[2] / 64;

  int* cursor = (int*)d_ws;                                        // M i32
  unsigned* rec = (unsigned*)(cursor + M);                         // M*CAP u32
  unsigned short* msg_bf = (unsigned short*)rec;                   // alias: rec consumed by gather
  unsigned short* zbf = (unsigned short*)(rec + (size_t)M * CAP);  // M*64 bf16
  unsigned short* fbf = zbf + (size_t)M * 64;                      // N*64 bf16
  unsigned short* HBt = fbf + (size_t)N * 64;                      // N*64 bf16 (ct-packed)
  short* bfZ = (short*)(HBt + (size_t)N * 64);                     // 12*512 bf16
  short* GF = bfZ + 12 * 512;                                      // 16*512 bf16
  short* WihF = GF + 16 * 512;                                     // 24*512 bf16
  short* WhhF = WihF + 24 * 512;                                   // 24*512 bf16
  int* slotbuf = (int*)(WhhF + 24 * 512);                          // N*8 i32

  long npairs = (long)N * 8;

  zero_cursor<<<128, 256, 0, stream>>>(cursor, M);

  prep_kernel<<<2048, 256, 0, stream>>>(z_lat, f_pts, sim_w1, sim_b1,
                                        gate_w1, W_ih, W_hh, cand,
                                        zbf, fbf, HBt, bfZ, GF, WihF, WhhF,
                                        slotbuf, cursor, M, npairs);

  int nwaves = (N * 8) / (16 * TPW);                               // 8192 waves
  pair_kernel<<<nwaves / 4, 256, 0, stream>>>(pts, zbf, centers, cand,
                                              sim_w2, bfZ, HBt, slotbuf, rec);

  gather_kernel<<<(M * 4) / 256, 256, 0, stream>>>(rec, cursor, fbf, msg_bf, M);

  stage2<<<M / 128, 512, 0, stream>>>(zbf, GF, WihF, WhhF,
                                      gate_b1, gate_w2, gate_b2, b_ih, b_hh,
                                      msg_bf, (float*)d_out);
}

// Round 16
// 108.616 us; speedup vs baseline: 1.0647x; 1.0647x over previous
//
#include <hip/hip_runtime.h>
#include <hip/hip_fp16.h>
#include <math.h>

// LatentVoxelGrid: N=65536 pts, M=131072 voxels, K=8 cand, D=64.
// prep  (cursor=0, z->zbf, bfZ + stage2 weight B-frags; hb spread over ALL blocks)
// pair  (TPW=4 preload-all, MFMA, batched softmax; cursor atomic in epilogue)
// gather(per-voxel sum -> normalized bf16 msg; msg aliases rec)
// stage2(gate+GRU, B-frags from L2-hot global, LDS = 2KB biases only)

typedef short bf16x8 __attribute__((ext_vector_type(8)));
typedef unsigned short u16x8 __attribute__((ext_vector_type(8)));
typedef float f32x4 __attribute__((ext_vector_type(4)));
#define MFMA __builtin_amdgcn_mfma_f32_16x16x32_bf16
#define CAP 32

__device__ __forceinline__ short f2bf(float f) {  // round-to-nearest-even
  unsigned u = __float_as_uint(f);
  unsigned r = (u + 0x7FFFu + ((u >> 16) & 1u)) >> 16;
  return (short)r;
}

__device__ __forceinline__ float bf2f(unsigned short h) {
  return __uint_as_float(((unsigned)h) << 16);
}

__device__ __forceinline__ float sigm(float x) { return 1.0f / (1.0f + __expf(-x)); }

// ---- prep: cursor=0, zbf, bfZ/GF/WihF/WhhF packs, HBt + fbf (balanced) ----
__global__ __launch_bounds__(256) void prep_kernel(
    const float* __restrict__ z, const float* __restrict__ f,
    const float* __restrict__ sim_w1, const float* __restrict__ sim_b1,
    const float* __restrict__ gate_w1, const float* __restrict__ W_ih,
    const float* __restrict__ W_hh,
    unsigned short* __restrict__ zbf, unsigned short* __restrict__ fbf,
    unsigned short* __restrict__ HBt, short* __restrict__ bfZ,
    short* __restrict__ GF, short* __restrict__ WihF, short* __restrict__ WhhF,
    int* __restrict__ cursor, int M)
{
  long tid = (long)blockIdx.x * 256 + threadIdx.x;
  long nthr = (long)gridDim.x * 256;

  for (long i = tid; i < M; i += nthr) cursor[i] = 0;

  long nz = (long)M * 64;
  for (long i = tid * 8; i < nz; i += nthr * 8) {
    float4 a = *(const float4*)&z[i];
    float4 b4 = *(const float4*)&z[i + 4];
    u16x8 o;
    o[0] = (unsigned short)f2bf(a.x);  o[1] = (unsigned short)f2bf(a.y);
    o[2] = (unsigned short)f2bf(a.z);  o[3] = (unsigned short)f2bf(a.w);
    o[4] = (unsigned short)f2bf(b4.x); o[5] = (unsigned short)f2bf(b4.y);
    o[6] = (unsigned short)f2bf(b4.z); o[7] = (unsigned short)f2bf(b4.w);
    *(u16x8*)&zbf[i] = o;
  }

  if (blockIdx.x == gridDim.x - 1 && threadIdx.x < 64) {  // sim_w1 z-part frags
    int lane = threadIdx.x;
    int lr = lane & 15, lg = lane >> 4;
#pragma unroll
    for (int ct = 0; ct < 4; ++ct)
#pragma unroll
      for (int kt = 0; kt < 3; ++kt) {
        bf16x8 b;
#pragma unroll
        for (int e = 0; e < 8; ++e) {
          int k = kt * 32 + lg * 8 + e;  // 0..95: [z(64) | delta(3) | pad]
          float v = (k < 67) ? sim_w1[(64 + k) * 64 + ct * 16 + lr] : 0.0f;
          b[e] = f2bf(v);
        }
        *(bf16x8*)&bfZ[(ct * 3 + kt) * 512 + lane * 8] = b;
      }
  }

  if (blockIdx.x >= 1024 && blockIdx.x < 1040) {  // stage2 weight B-frags
    int fb = (blockIdx.x - 1024) * 4 + (threadIdx.x >> 6);  // 0..63
    int lane = threadIdx.x & 63, lr = lane & 15, lg = lane >> 4;
    bf16x8 o;
    if (fb < 16) {            // gate_w1 (128,64): frag = ct*4+kt
      int ct = fb >> 2, kt = fb & 3;
#pragma unroll
      for (int e = 0; e < 8; ++e)
        o[e] = f2bf(gate_w1[(kt * 32 + lg * 8 + e) * 64 + ct * 16 + lr]);
      *(bf16x8*)&GF[fb * 512 + lane * 8] = o;
    } else if (fb < 40) {     // W_ih (192,64): frag = g*8 + ct*2 + k2
      int q = fb - 16, g = q >> 3, ct = (q >> 1) & 3, k2 = q & 1;
      int row = g * 64 + ct * 16 + lr;
#pragma unroll
      for (int e = 0; e < 8; ++e)
        o[e] = f2bf(W_ih[row * 64 + k2 * 32 + lg * 8 + e]);
      *(bf16x8*)&WihF[q * 512 + lane * 8] = o;
    } else {                  // W_hh (192,64)
      int q = fb - 40, g = q >> 3, ct = (q >> 1) & 3, k2 = q & 1;
      int row = g * 64 + ct * 16 + lr;
#pragma unroll
      for (int e = 0; e < 8; ++e)
        o[e] = f2bf(W_hh[row * 64 + k2 * 32 + lg * 8 + e]);
      *(bf16x8*)&WhhF[q * 512 + lane * 8] = o;
    }
  }

  // hb: 4096 wave-tasks spread over ALL blocks (even global wave -> task g>>1)
  {
    int g = blockIdx.x * 4 + (threadIdx.x >> 6);
    if ((g & 1) == 0) {
      int wave = g >> 1;   // 0..4095
      int lane = threadIdx.x & 63;
      int lr = lane & 15, lg = lane >> 4;
      int n0 = wave * 16;

      bf16x8 bf[8];  // f-part B frags (sim_w1 is L2-hot)
#pragma unroll
      for (int ct = 0; ct < 4; ++ct)
#pragma unroll
        for (int kt = 0; kt < 2; ++kt) {
          bf16x8 bb;
#pragma unroll
          for (int e = 0; e < 8; ++e)
            bb[e] = f2bf(sim_w1[(kt * 32 + lg * 8 + e) * 64 + ct * 16 + lr]);
          bf[ct * 2 + kt] = bb;
        }

      bf16x8 a[2];
#pragma unroll
      for (int kt = 0; kt < 2; ++kt) {
        const float* src = &f[(long)(n0 + lr) * 64 + kt * 32 + lg * 8];
        float4 v0 = *(const float4*)src;
        float4 v1 = *(const float4*)(src + 4);
        bf16x8 t;
        t[0] = f2bf(v0.x); t[1] = f2bf(v0.y); t[2] = f2bf(v0.z); t[3] = f2bf(v0.w);
        t[4] = f2bf(v1.x); t[5] = f2bf(v1.y); t[6] = f2bf(v1.z); t[7] = f2bf(v1.w);
        a[kt] = t;
      }
      *(bf16x8*)&fbf[(long)(n0 + lr) * 64 + lg * 8] = a[0];
      *(bf16x8*)&fbf[(long)(n0 + lr) * 64 + 32 + lg * 8] = a[1];

      f32x4 acc[4] = {{0,0,0,0},{0,0,0,0},{0,0,0,0},{0,0,0,0}};
#pragma unroll
      for (int ct = 0; ct < 4; ++ct) {
        acc[ct] = MFMA(a[0], bf[ct * 2 + 0], acc[ct], 0, 0, 0);
        acc[ct] = MFMA(a[1], bf[ct * 2 + 1], acc[ct], 0, 0, 0);
      }
      float b10 = sim_b1[lr], b11 = sim_b1[16 + lr];
      float b12 = sim_b1[32 + lr], b13 = sim_b1[48 + lr];
#pragma unroll
      for (int e = 0; e < 4; ++e) {
        unsigned lo = (unsigned)(unsigned short)f2bf(acc[0][e] + b10)
                    | ((unsigned)(unsigned short)f2bf(acc[1][e] + b11) << 16);
        unsigned hi = (unsigned)(unsigned short)f2bf(acc[2][e] + b12)
                    | ((unsigned)(unsigned short)f2bf(acc[3][e] + b13) << 16);
        *(uint2*)&HBt[(long)(n0 + lg * 4 + e) * 64 + lr * 4] = make_uint2(lo, hi);
      }
    }
  }
}

// ---- pair: preload all tiles -> MFMA all -> batched softmax -> records ----
#define TPW 4
__global__ __launch_bounds__(256) void pair_kernel(
    const float* __restrict__ pts, const unsigned short* __restrict__ zbf,
    const float* __restrict__ centers, const int* __restrict__ cand_idx,
    const float* __restrict__ sim_w2, const short* __restrict__ bfZ,
    const unsigned short* __restrict__ HBt,
    int* __restrict__ cursor, unsigned* __restrict__ rec)
{
  int wave = (blockIdx.x * 256 + threadIdx.x) >> 6;
  int lane = threadIdx.x & 63;
  int lr = lane & 15, lg = lane >> 4;

  // lane owns the record of pair wave*64+lane (tile lg, row lr)
  int call = cand_idx[wave * 64 + lane];

  bf16x8 b[12];
#pragma unroll
  for (int i = 0; i < 12; ++i) b[i] = *(const bf16x8*)&bfZ[i * 512 + lane * 8];
  float w2c[4];
#pragma unroll
  for (int ct = 0; ct < 4; ++ct) w2c[ct] = sim_w2[ct * 16 + lr];

  // ---- preload phase: ALL tiles' operands issued back-to-back ----
  int c[TPW];
  bf16x8 a0[TPW], a1[TPW], ad[TPW];
  uint2 h2[TPW];
#pragma unroll
  for (int t = 0; t < TPW; ++t) {
    c[t] = __shfl(call, t * 16 + lr, 64);
    a0[t] = *(const bf16x8*)&zbf[(long)c[t] * 64 + lg * 8];
    a1[t] = *(const bf16x8*)&zbf[(long)c[t] * 64 + 32 + lg * 8];
    h2[t] = *(const uint2*)&HBt[((long)(wave * TPW + t) * 2 + (lg >> 1)) * 64 + lr * 4];
    bf16x8 tt = {0, 0, 0, 0, 0, 0, 0, 0};
    if (lg == 0) {
      int n = (wave * TPW + t) * 2 + (lr >> 3);
      tt[0] = f2bf(pts[n * 3 + 0] - centers[c[t] * 3 + 0]);
      tt[1] = f2bf(pts[n * 3 + 1] - centers[c[t] * 3 + 1]);
      tt[2] = f2bf(pts[n * 3 + 2] - centers[c[t] * 3 + 2]);
    }
    ad[t] = tt;
  }

  // ---- MFMA + w2-dot phase ----
  f32x4 part[TPW];
#pragma unroll
  for (int t = 0; t < TPW; ++t) {
    f32x4 acc[4] = {{0,0,0,0},{0,0,0,0},{0,0,0,0},{0,0,0,0}};
#pragma unroll
    for (int ct = 0; ct < 4; ++ct) {
      acc[ct] = MFMA(a0[t], b[ct * 3 + 0], acc[ct], 0, 0, 0);
      acc[ct] = MFMA(a1[t], b[ct * 3 + 1], acc[ct], 0, 0, 0);
      acc[ct] = MFMA(ad[t], b[ct * 3 + 2], acc[ct], 0, 0, 0);
    }
    float hb[4];
    hb[0] = bf2f((unsigned short)(h2[t].x));
    hb[1] = bf2f((unsigned short)(h2[t].x >> 16));
    hb[2] = bf2f((unsigned short)(h2[t].y));
    hb[3] = bf2f((unsigned short)(h2[t].y >> 16));
    f32x4 p = {0.f, 0.f, 0.f, 0.f};
#pragma unroll
    for (int ct = 0; ct < 4; ++ct)
#pragma unroll
      for (int e = 0; e < 4; ++e)
        p[e] = fmaf(fmaxf(acc[ct][e] + hb[ct], 0.0f), w2c[ct], p[e]);
    part[t] = p;
  }

  // ---- batched softmax phase (4 independent chains) ----
  float wrow[TPW];
#pragma unroll
  for (int t = 0; t < TPW; ++t) {
    f32x4 p = part[t];
#pragma unroll
    for (int m = 1; m <= 8; m <<= 1)
#pragma unroll
      for (int e = 0; e < 4; ++e) p[e] += __shfl_xor(p[e], m, 64);
    float other[4];
#pragma unroll
    for (int e = 0; e < 4; ++e) other[e] = __shfl_xor(p[e], 16, 64);
    float mx = p[0];
#pragma unroll
    for (int e = 1; e < 4; ++e) mx = fmaxf(mx, p[e]);
#pragma unroll
    for (int e = 0; e < 4; ++e) mx = fmaxf(mx, other[e]);
    float ex[4], se = 0.f, so = 0.f;
#pragma unroll
    for (int e = 0; e < 4; ++e) {
      ex[e] = __expf((p[e] - mx) * (1.0f / 0.3f));
      se += ex[e];
      so += __expf((other[e] - mx) * (1.0f / 0.3f));
    }
    float inv = 1.0f / (se + so);
    int srcl = (lane >> 2) << 4;
    float t0 = __shfl(ex[0] * inv, srcl, 64);
    float t1 = __shfl(ex[1] * inv, srcl, 64);
    float t2 = __shfl(ex[2] * inv, srcl, 64);
    float t3 = __shfl(ex[3] * inv, srcl, 64);
    int esel = lane & 3;
    wrow[t] = esel == 0 ? t0 : esel == 1 ? t1 : esel == 2 ? t2 : t3;
  }

  // ---- epilogue: cursor atomic + route weight + record ----
  int slot = atomicAdd(&cursor[call], 1);

  float v0 = __shfl(wrow[0], lr, 64);
  float v1 = __shfl(wrow[1], lr, 64);
  float v2 = __shfl(wrow[2], lr, 64);
  float v3 = __shfl(wrow[3], lr, 64);
  float wv = lg == 0 ? v0 : lg == 1 ? v1 : lg == 2 ? v2 : v3;

  if (slot < CAP) {
    int n_pt = wave * 8 + 2 * lg + (lr >> 3);
    unsigned short wh = __half_as_ushort(__float2half(wv));
    rec[(long)call * CAP + slot] = ((unsigned)n_pt << 16) | (unsigned)wh;
  }
}

// ---- gather: msg[v] = (Sum w*f[n]) / (Sum w + eps); msg ALIASES rec rows ----
__global__ __launch_bounds__(256) void gather_kernel(
    const unsigned* __restrict__ rec, const int* __restrict__ cursor,
    const unsigned short* __restrict__ fbf, unsigned short* __restrict__ msg_bf,
    int mvox)
{
  int tid = blockIdx.x * 256 + threadIdx.x;
  int row = tid >> 2, seg = tid & 3;  // 4 threads per voxel, 16 cols each
  if (row >= mvox) return;

  int cnt = cursor[row];
  cnt = cnt < CAP ? cnt : CAP;
  const unsigned* rp = &rec[(long)row * CAP];

  float acc[16];
#pragma unroll
  for (int j = 0; j < 16; ++j) acc[j] = 0.f;
  float ws = 0.f;

  for (int i0 = 0; i0 < cnt; i0 += 4) {
    uint4 r4 = *(const uint4*)&rp[i0];
    unsigned rr0 = r4.x, rr1 = r4.y, rr2 = r4.z, rr3 = r4.w;
#pragma unroll
    for (int j = 0; j < 4; ++j) {
      unsigned r = j == 0 ? rr0 : j == 1 ? rr1 : j == 2 ? rr2 : rr3;
      if (i0 + j < cnt) {
        float w = __half2float(__ushort_as_half((unsigned short)(r & 0xffffu)));
        int n = r >> 16;
        ws += w;
        const u16x8* fp = (const u16x8*)&fbf[(long)n * 64 + seg * 16];
        u16x8 f0 = fp[0], f1 = fp[1];
#pragma unroll
        for (int k = 0; k < 8; ++k) {
          acc[k]     = fmaf(w, bf2f(f0[k]), acc[k]);
          acc[8 + k] = fmaf(w, bf2f(f1[k]), acc[8 + k]);
        }
      }
    }
  }
  float inv = 1.0f / (ws + 1e-6f);
  u16x8 o0, o1;
#pragma unroll
  for (int j = 0; j < 8; ++j) {
    o0[j] = (unsigned short)f2bf(acc[j] * inv);
    o1[j] = (unsigned short)f2bf(acc[8 + j] * inv);
  }
  *(u16x8*)&msg_bf[(long)row * 64 + seg * 16] = o0;
  *(u16x8*)&msg_bf[(long)row * 64 + seg * 16 + 8] = o1;
}

// ---- Stage 2: gate MLP + GRU; weights as L2-hot global B-frags; LDS=biases ----
__global__ __launch_bounds__(512)
__attribute__((amdgpu_waves_per_eu(2)))
void stage2(
    const unsigned short* __restrict__ zbf,
    const short* __restrict__ GF, const short* __restrict__ WihF,
    const short* __restrict__ WhhF,
    const float* __restrict__ gate_b1, const float* __restrict__ gate_w2,
    const float* __restrict__ gate_b2,
    const float* __restrict__ b_ih, const float* __restrict__ b_hh,
    const unsigned short* __restrict__ msg_bf,
    float* __restrict__ out)
{
  __shared__ float gb1s[64], gw2s[64], bihs[192], bhhs[192];
  __shared__ float gb2s;

  int t = threadIdx.x;
  if (t < 64) { gb1s[t] = gate_b1[t]; gw2s[t] = gate_w2[t]; }
  if (t < 192) { bihs[t] = b_ih[t]; bhhs[t] = b_hh[t]; }
  if (t == 0) gb2s = gate_b2[0];
  __syncthreads();

  int wid = t >> 6, lane = t & 63;
  int lr = lane & 15, lg = lane >> 4;

  int rowbase = blockIdx.x * 128 + wid * 16;
  long abase = (long)(rowbase + lr) * 64;
  bf16x8 a0 = *(const bf16x8*)&zbf[abase + lg * 8];
  bf16x8 a1 = *(const bf16x8*)&zbf[abase + 32 + lg * 8];
  bf16x8 a2 = *(const bf16x8*)&msg_bf[abase + lg * 8];
  bf16x8 a3 = *(const bf16x8*)&msg_bf[abase + 32 + lg * 8];

  // ---- pass 1: gate ----
  f32x4 usum = {0.f, 0.f, 0.f, 0.f};
#pragma unroll 1
  for (int ct = 0; ct < 4; ++ct) {
    f32x4 au = {0, 0, 0, 0};
    au = MFMA(a0, *(const bf16x8*)&GF[(ct * 4 + 0) * 512 + lane * 8], au, 0, 0, 0);
    au = MFMA(a1, *(const bf16x8*)&GF[(ct * 4 + 1) * 512 + lane * 8], au, 0, 0, 0);
    au = MFMA(a2, *(const bf16x8*)&GF[(ct * 4 + 2) * 512 + lane * 8], au, 0, 0, 0);
    au = MFMA(a3, *(const bf16x8*)&GF[(ct * 4 + 3) * 512 + lane * 8], au, 0, 0, 0);
    int c = ct * 16 + lr;
#pragma unroll
    for (int e = 0; e < 4; ++e)
      usum[e] += fmaxf(au[e] + gb1s[c], 0.0f) * gw2s[c];
  }
#pragma unroll
  for (int m = 1; m <= 8; m <<= 1)
#pragma unroll
    for (int e = 0; e < 4; ++e) {
      float v = usum[e];
      usum[e] = v + __shfl_xor(v, m, 64);
    }
  float gate[4];
#pragma unroll
  for (int e = 0; e < 4; ++e) gate[e] = sigm(usum[e] + gb2s);

  // ---- pass 2: GRU, write out per ct ----
#pragma unroll 1
  for (int ct = 0; ct < 4; ++ct) {
    f32x4 air = {0,0,0,0}, aiz = {0,0,0,0}, ain = {0,0,0,0};
    f32x4 ahr = {0,0,0,0}, ahz = {0,0,0,0}, ahn = {0,0,0,0};
#pragma unroll
    for (int k2 = 0; k2 < 2; ++k2) {
      bf16x8 amg = k2 ? a3 : a2;
      bf16x8 az_ = k2 ? a1 : a0;
      int base = ct * 2 + k2;
      air = MFMA(amg, *(const bf16x8*)&WihF[(      base) * 512 + lane * 8], air, 0, 0, 0);
      aiz = MFMA(amg, *(const bf16x8*)&WihF[( 8 +  base) * 512 + lane * 8], aiz, 0, 0, 0);
      ain = MFMA(amg, *(const bf16x8*)&WihF[(16 +  base) * 512 + lane * 8], ain, 0, 0, 0);
      ahr = MFMA(az_, *(const bf16x8*)&WhhF[(      base) * 512 + lane * 8], ahr, 0, 0, 0);
      ahz = MFMA(az_, *(const bf16x8*)&WhhF[( 8 +  base) * 512 + lane * 8], ahz, 0, 0, 0);
      ahn = MFMA(az_, *(const bf16x8*)&WhhF[(16 +  base) * 512 + lane * 8], ahn, 0, 0, 0);
    }
    int c = ct * 16 + lr;
#pragma unroll
    for (int e = 0; e < 4; ++e) {
      float zv = bf2f(zbf[(long)(rowbase + lg * 4 + e) * 64 + c]);
      float rr = sigm(air[e] + bihs[c] + ahr[e] + bhhs[c]);
      float zg = sigm(aiz[e] + bihs[64 + c] + ahz[e] + bhhs[64 + c]);
      float nn = tanhf(ain[e] + bihs[128 + c] + rr * (ahn[e] + bhhs[128 + c]));
      float hnew = (1.0f - zg) * nn + zg * zv;
      out[(long)(rowbase + lg * 4 + e) * 64 + c] = zv + gate[e] * (hnew - zv);
    }
  }
}

extern "C" void kernel_launch(void* const* d_in, const int* in_sizes, int n_in,
                              void* d_out, int out_size, void* d_ws, size_t ws_size,
                              hipStream_t stream) {
  const float* f_pts   = (const float*)d_in[0];
  const float* pts     = (const float*)d_in[1];
  const float* z_lat   = (const float*)d_in[2];
  const float* centers = (const float*)d_in[3];
  const int*   cand    = (const int*)d_in[4];
  const float* sim_w1  = (const float*)d_in[5];
  const float* sim_b1  = (const float*)d_in[6];
  const float* sim_w2  = (const float*)d_in[7];
  // d_in[8] = sim_b2: uniform softmax shift, unused
  const float* gate_w1 = (const float*)d_in[9];
  const float* gate_b1 = (const float*)d_in[10];
  const float* gate_w2 = (const float*)d_in[11];
  const float* gate_b2 = (const float*)d_in[12];
  const float* W_ih    = (const float*)d_in[13];
  const float* W_hh    = (const float*)d_in[14];
  const float* b_ih    = (const float*)d_in[15];
  const float* b_hh    = (const float*)d_in[16];

  int N = in_sizes[0] / 64;
  int M = in_sizes[2] / 64;

  int* cursor = (int*)d_ws;                                        // M i32
  unsigned* rec = (unsigned*)(cursor + M);                         // M*CAP u32
  unsigned short* msg_bf = (unsigned short*)rec;                   // alias: rec consumed by gather
  unsigned short* zbf = (unsigned short*)(rec + (size_t)M * CAP);  // M*64 bf16
  unsigned short* fbf = zbf + (size_t)M * 64;                      // N*64 bf16
  unsigned short* HBt = fbf + (size_t)N * 64;                      // N*64 bf16 (ct-packed)
  short* bfZ = (short*)(HBt + (size_t)N * 64);                     // 12*512 bf16
  short* GF = bfZ + 12 * 512;                                      // 16*512 bf16
  short* WihF = GF + 16 * 512;                                     // 24*512 bf16
  short* WhhF = WihF + 24 * 512;                                   // 24*512 bf16

  prep_kernel<<<2048, 256, 0, stream>>>(z_lat, f_pts, sim_w1, sim_b1,
                                        gate_w1, W_ih, W_hh,
                                        zbf, fbf, HBt, bfZ, GF, WihF, WhhF,
                                        cursor, M);

  int nwaves = (N * 8) / (16 * TPW);                               // 8192 waves
  pair_kernel<<<nwaves / 4, 256, 0, stream>>>(pts, zbf, centers, cand,
                                              sim_w2, bfZ, HBt, cursor, rec);

  gather_kernel<<<(M * 4) / 256, 256, 0, stream>>>(rec, cursor, fbf, msg_bf, M);

  stage2<<<M / 128, 512, 0, stream>>>(zbf, GF, WihF, WhhF,
                                      gate_b1, gate_w2, gate_b2, b_ih, b_hh,
                                      msg_bf, (float*)d_out);
}